// Round 16
// baseline (203.733 us; speedup 1.0000x reference)
//
#include <hip/hip_runtime.h>

// GCN 3-layer forward — Round 26 (resubmit; infra failure last round): R25
// base (199.1us; fp16 table + packed scatter + 2-pass scatter) with prescale
// FUSED into scan_finish as a grid-stride tail (identical indexing/arithmetic;
// dinv re-read is L2-hot). 8 dispatches (was 9). Zero arithmetic change ->
// absmax 2.441406e-4.
//   Ledger: fp16 table -25us, pack -2.6, 4-pass scatter -5; layer levers
//   (prefetch/occupancy/payload/stream-bytes/issue-count) all null.

#define FEAT 64
#define SCAN_B 1024
#define STILE 68   // s_tile stride: breaks 4-way LDS bank conflict on k-loop

typedef int      v4i __attribute__((ext_vector_type(4)));
typedef float    v4f __attribute__((ext_vector_type(4)));
typedef _Float16 v4h __attribute__((ext_vector_type(4)));

// ---------- CSR build ----------
// degree count; atomic return = within-row rank; emit pack=(rank<<16)|src.
__global__ void deg_pack_kernel(const int* __restrict__ dst, const int* __restrict__ src,
                                int* __restrict__ cnt, int* __restrict__ pack, int E4) {
    int i = blockIdx.x * blockDim.x + threadIdx.x;
    if (i < E4) {
        v4i d = __builtin_nontemporal_load(((const v4i*)dst) + i);
        v4i s = __builtin_nontemporal_load(((const v4i*)src) + i);
        v4i r;
        r[0] = (atomicAdd(&cnt[d[0]], 1) << 16) | s[0];
        r[1] = (atomicAdd(&cnt[d[1]], 1) << 16) | s[1];
        r[2] = (atomicAdd(&cnt[d[2]], 1) << 16) | s[2];
        r[3] = (atomicAdd(&cnt[d[3]], 1) << 16) | s[3];
        __builtin_nontemporal_store(r, ((v4i*)pack) + i);
    }
}

// Pass 1: exclusive scan over counts PADDED to multiple of 8 -> rowptr
// (chunk-local), bsum. dinv from RAW count: rsqrt(1+cnt).
__global__ __launch_bounds__(SCAN_B) void scan_partial_kernel(
    const int* __restrict__ cnt, int* __restrict__ rowptr,
    int* __restrict__ bsum, float* __restrict__ dinv, int n) {
    __shared__ int wsum[SCAN_B / 64 + 1];
    const int tid  = threadIdx.x;
    const int lane = tid & 63;
    const int wid  = tid >> 6;
    const int i = blockIdx.x * SCAN_B + tid;

    int vr = (i < n) ? cnt[i] : 0;
    if (i < n) dinv[i] = rsqrtf((float)(1 + vr));
    int v = (vr + 7) & ~7;            // pad each list to multiple of 8
    int incl = v;
#pragma unroll
    for (int off = 1; off < 64; off <<= 1) {
        int t = __shfl_up(incl, off, 64);
        if (lane >= off) incl += t;
    }
    if (lane == 63) wsum[wid] = incl;
    __syncthreads();
    if (tid == 0) {
        int run = 0;
#pragma unroll
        for (int w = 0; w < SCAN_B / 64; ++w) { int t = wsum[w]; wsum[w] = run; run += t; }
        wsum[SCAN_B / 64] = run;
        bsum[blockIdx.x] = run;
    }
    __syncthreads();
    if (i < n) rowptr[i] = incl - v + wsum[wid];
}

// Pass 2 (fused): bsum wave-scan -> block offset; rowptr finalize; pad fill;
// THEN grid-stride prescale tail: P1[q] = fp16(x[q]*dinv[q>>4]) with the
// exact indexing/arithmetic of the old prescale kernel, + row-N zeroing.
__global__ __launch_bounds__(SCAN_B) void scan_finish_kernel(
    const int* __restrict__ cnt, int* __restrict__ rowptr,
    const int* __restrict__ bsum, int* __restrict__ col,
    const float* __restrict__ x, const float* __restrict__ dinv,
    _Float16* __restrict__ P1, _Float16* __restrict__ P2,
    int n, int nb, int dummy, int nq) {
    __shared__ int s_off, s_tot;
    const int tid = threadIdx.x;
    if (tid < 64) {
        int v = (tid < nb) ? bsum[tid] : 0;
        int incl = v;
#pragma unroll
        for (int off = 1; off < 64; off <<= 1) {
            int t = __shfl_up(incl, off, 64);
            if ((tid & 63) >= off) incl += t;
        }
        if (tid == (int)blockIdx.x) s_off = incl - v;  // exclusive offset
        if (tid == 63) s_tot = incl;                   // grand total
    }
    __syncthreads();
    const int i = blockIdx.x * SCAN_B + tid;
    if (i < n) {
        const int rp = rowptr[i] + s_off;
        rowptr[i] = rp;
        const int c = cnt[i];
        const int e = rp + ((c + 7) & ~7);
        for (int p = rp + c; p < e; ++p) col[p] = dummy;
    }
    if (i == 0) rowptr[n] = s_tot;

    // ---- fused prescale (grid-stride; identical pattern to old kernel) ----
    const int stride = gridDim.x * SCAN_B;
    for (int q = i; q < nq + 16; q += stride) {
        if (q < nq) {
            float d = dinv[q >> 4];
            float4 v = ((const float4*)x)[q];
            v4h o;
            o[0] = (_Float16)(v.x * d); o[1] = (_Float16)(v.y * d);
            o[2] = (_Float16)(v.z * d); o[3] = (_Float16)(v.w * d);
            *(v4h*)&P1[(size_t)q * 4] = o;
        } else {
            v4h z = {(_Float16)0.f, (_Float16)0.f, (_Float16)0.f, (_Float16)0.f};
            *(v4h*)&P1[(size_t)q * 4] = z;   // row N of P1
            *(v4h*)&P2[(size_t)q * 4] = z;   // row N of P2
        }
    }
}

// dst-range-partitioned scatter, 2 passes: q = blockIdx&1 owns dst nodes
// [q*qn, (q+1)*qn) -> contiguous col region. rowptr gather is L2-resident.
// pack = (rank<<16)|src.
__global__ void scatter_kernel(const int* __restrict__ dst, const int* __restrict__ pack,
                               const int* __restrict__ rowptr,
                               int* __restrict__ col, int E4, int qn, int n) {
    const int q = blockIdx.x & 1;
    const int i = (blockIdx.x >> 1) * blockDim.x + threadIdx.x;
    const int nlo = q * qn;
    const int nhi = (nlo + qn < n) ? nlo + qn : n;
    if (i < E4) {
        v4i d = __builtin_nontemporal_load(((const v4i*)dst) + i);
        v4i pk = __builtin_nontemporal_load(((const v4i*)pack) + i);
#pragma unroll
        for (int j = 0; j < 4; ++j) {
            if (d[j] >= nlo && d[j] < nhi) {
                col[rowptr[d[j]] + (pk[j] >> 16)] = pk[j] & 0xFFFF;
            }
        }
    }
}

// ---------- fused layer: fp16 gather-sum (fp32 acc) -> LDS GEMM -> epilogue --
// 16 nodes/block, 16 lanes/node (4 halves = 8B/lane). Lists padded to x8:
// branch-free 8-wide loop, col read as 2x int4 (cached: broadcast across the
// node's 16 lanes, reused by all 3 layers), 8 gathers in flight, 4 independent
// fp32 accumulators. Dummy entries hit zeroed row N. Table pre-scaled by dinv.
template<int INTER>
__global__ __launch_bounds__(256) void layer_kernel(
    const int* __restrict__ rowptr, const int* __restrict__ col,
    const float* __restrict__ dinv, const _Float16* __restrict__ Xs,
    const float* __restrict__ W, const float* __restrict__ bias,
    void* __restrict__ outv, int n) {
    __shared__ float w_lds[FEAT * FEAT];   // [k][c]
    __shared__ float s_tile[16 * STILE];   // [r][k], padded

    const int t = threadIdx.x;
#pragma unroll
    for (int i = 0; i < 4; ++i) {
        int idx = (i * 256 + t) * 4;
        *(float4*)&w_lds[idx] = *(const float4*)&W[idx];
    }
    __syncthreads();   // W visible; nothing else needs a barrier below

    const int r  = t >> 4;       // local node 0..15
    const int c4 = t & 15;       // feature group (4 halves)
    const int g  = blockIdx.x * 16 + r;
    if (g >= n) return;
    const int f = c4 * 4;
    const _Float16* __restrict__ Hf = Xs + f;

    // self-loop term (table pre-scaled)
    const v4h sh = *(const v4h*)&Hf[(size_t)g * FEAT];
    float4 a0 = make_float4((float)sh[0], (float)sh[1], (float)sh[2], (float)sh[3]);
    float4 a1 = make_float4(0.f, 0.f, 0.f, 0.f);
    float4 a2 = make_float4(0.f, 0.f, 0.f, 0.f);
    float4 a3 = make_float4(0.f, 0.f, 0.f, 0.f);

    int p = rowptr[g];
    const int end = rowptr[g + 1];   // end - p is a multiple of 8

    for (; p < end; p += 8) {
        const v4i c0 = *(const v4i*)&col[p];
        const v4i c1 = *(const v4i*)&col[p + 4];
        const v4h h0 = *(const v4h*)&Hf[(size_t)c0[0] * FEAT];
        const v4h h1 = *(const v4h*)&Hf[(size_t)c0[1] * FEAT];
        const v4h h2 = *(const v4h*)&Hf[(size_t)c0[2] * FEAT];
        const v4h h3 = *(const v4h*)&Hf[(size_t)c0[3] * FEAT];
        const v4h h4 = *(const v4h*)&Hf[(size_t)c1[0] * FEAT];
        const v4h h5 = *(const v4h*)&Hf[(size_t)c1[1] * FEAT];
        const v4h h6 = *(const v4h*)&Hf[(size_t)c1[2] * FEAT];
        const v4h h7 = *(const v4h*)&Hf[(size_t)c1[3] * FEAT];
        a0.x += (float)h0[0]; a0.y += (float)h0[1]; a0.z += (float)h0[2]; a0.w += (float)h0[3];
        a1.x += (float)h1[0]; a1.y += (float)h1[1]; a1.z += (float)h1[2]; a1.w += (float)h1[3];
        a2.x += (float)h2[0]; a2.y += (float)h2[1]; a2.z += (float)h2[2]; a2.w += (float)h2[3];
        a3.x += (float)h3[0]; a3.y += (float)h3[1]; a3.z += (float)h3[2]; a3.w += (float)h3[3];
        a0.x += (float)h4[0]; a0.y += (float)h4[1]; a0.z += (float)h4[2]; a0.w += (float)h4[3];
        a1.x += (float)h5[0]; a1.y += (float)h5[1]; a1.z += (float)h5[2]; a1.w += (float)h5[3];
        a2.x += (float)h6[0]; a2.y += (float)h6[1]; a2.z += (float)h6[2]; a2.w += (float)h6[3];
        a3.x += (float)h7[0]; a3.y += (float)h7[1]; a3.z += (float)h7[2]; a3.w += (float)h7[3];
    }
    float4 S = make_float4((a0.x + a1.x) + (a2.x + a3.x),
                           (a0.y + a1.y) + (a2.y + a3.y),
                           (a0.z + a1.z) + (a2.z + a3.z),
                           (a0.w + a1.w) + (a2.w + a3.w));
    *(float4*)&s_tile[r * STILE + f] = S;
    // no __syncthreads: wave w reads only rows 4w..4w+3, which it wrote

    // in-block GEMM: T[r][f..f+3] = sum_k S[r][k] * W[k][f..f+3]
    float4 acc = make_float4(0.f, 0.f, 0.f, 0.f);
#pragma unroll
    for (int k = 0; k < FEAT; ++k) {
        const float sv = s_tile[r * STILE + k];
        const float4 wv = *(const float4*)&w_lds[k * FEAT + f];
        acc.x += sv * wv.x; acc.y += sv * wv.y;
        acc.z += sv * wv.z; acc.w += sv * wv.w;
    }

    const float dg = dinv[g];
    const float4 bv = *(const float4*)&bias[f];
    float4 o = make_float4(acc.x * dg + bv.x, acc.y * dg + bv.y,
                           acc.z * dg + bv.z, acc.w * dg + bv.w);
    if (INTER) {   // ReLU, then pre-scale for next layer's gather; store fp16
        o.x = fmaxf(o.x, 0.f) * dg; o.y = fmaxf(o.y, 0.f) * dg;
        o.z = fmaxf(o.z, 0.f) * dg; o.w = fmaxf(o.w, 0.f) * dg;
        _Float16* o16 = (_Float16*)outv;
        v4h ov;
        ov[0] = (_Float16)o.x; ov[1] = (_Float16)o.y;
        ov[2] = (_Float16)o.z; ov[3] = (_Float16)o.w;
        *(v4h*)&o16[(size_t)g * FEAT + f] = ov;   // cached: next layer's table
    } else {
        float* o32 = (float*)outv;
        *(float4*)&o32[(size_t)g * FEAT + f] = o;
    }
}

extern "C" void kernel_launch(void* const* d_in, const int* in_sizes, int n_in,
                              void* d_out, int out_size, void* d_ws, size_t ws_size,
                              hipStream_t stream) {
    const float* x  = (const float*)d_in[0];
    const int*   ei = (const int*)d_in[1];
    const float* W0 = (const float*)d_in[2];
    const float* b0 = (const float*)d_in[3];
    const float* W1 = (const float*)d_in[4];
    const float* b1 = (const float*)d_in[5];
    const float* W2 = (const float*)d_in[6];
    const float* b2 = (const float*)d_in[7];
    float* out = (float*)d_out;

    const int N = in_sizes[0] / FEAT;   // 50000
    const int E = in_sizes[1] / 2;      // 800000 (divisible by 4)
    const int* src = ei;
    const int* dst = ei + E;

    const int nbScan = (N + SCAN_B - 1) / SCAN_B;   // 49 (<= 64 for scan_finish)
    const int Ecap = E + 8 * N;                      // padded col capacity

    // workspace layout (64B-aligned regions)
    char* w = (char*)d_ws;
    auto take = [&](size_t bytes) { char* p = w; w += (bytes + 63) & ~(size_t)63; return p; };
    int*      cnt    = (int*)take(sizeof(int) * (size_t)N);
    int*      rowptr = (int*)take(sizeof(int) * (size_t)(N + 1));
    int*      bsum   = (int*)take(sizeof(int) * (size_t)(nbScan + 1));
    int*      col    = (int*)take(sizeof(int) * (size_t)Ecap);
    float*    dinv   = (float*)take(sizeof(float) * (size_t)N);
    _Float16* P1     = (_Float16*)take(sizeof(_Float16) * ((size_t)(N + 1) * FEAT));
    _Float16* P2     = (_Float16*)take(sizeof(_Float16) * ((size_t)(N + 1) * FEAT));
    int*      pack   = (int*)P2;   // alias: pack (3.2MB) sits in P2[0..3.2MB);
                                   // P2 row-N zeroing (offset 6.4MB) and
                                   // layer-0's P2 writes happen after scatter
                                   // consumed pack (stream-ordered)

    const int tB = 256;
    const int E4  = E / 4;
    const int gE4 = (E4 + tB - 1) / tB;
    const int g16 = (N + 15) / 16;
    const int qn  = (N + 1) / 2;        // nodes per scatter partition (2 passes)
    const int nq  = N * FEAT / 4;

    // CSR build (shared by all 3 layers)
    hipMemsetAsync(cnt, 0, sizeof(int) * (size_t)N, stream);
    deg_pack_kernel<<<gE4, tB, 0, stream>>>(dst, src, cnt, pack, E4);
    scan_partial_kernel<<<nbScan, SCAN_B, 0, stream>>>(cnt, rowptr, bsum, dinv, N);
    scan_finish_kernel<<<nbScan, SCAN_B, 0, stream>>>(cnt, rowptr, bsum, col,
                                                      x, dinv, P1, P2, N, nbScan, N, nq);
    scatter_kernel<<<gE4 * 2, tB, 0, stream>>>(dst, pack, rowptr, col, E4, qn, N);

    // fused layers
    layer_kernel<1><<<g16, tB, 0, stream>>>(rowptr, col, dinv, P1, W0, b0, P2, N);
    layer_kernel<1><<<g16, tB, 0, stream>>>(rowptr, col, dinv, P2, W1, b1, P1, N);
    layer_kernel<0><<<g16, tB, 0, stream>>>(rowptr, col, dinv, P1, W2, b2, out, N);
}

// Round 18
// 201.481 us; speedup vs baseline: 1.0112x; 1.0112x over previous
//
#include <hip/hip_runtime.h>

// GCN 3-layer forward — Round 28: calibrated fp8 retry. R27 (all-fp8) failed
// at 1.40e-3 vs threshold 9.47e-4 -> per-fp8-table error ~4-7e-4. This round:
// fp8 E4M3 for ONLY layer 0's table (x -> P8 at prescale; 64B row = 1 line,
// 3.2MB L2-resident); layers 1,2 keep the proven fp16 tables. Predicted
// absmax ~7e-4 < threshold. Chain: P8(fp8) ->L0-> P2h(fp16) ->L1-> P1h(fp16)
// ->L2-> out(fp32). Base structure = R25 (199.1us proven).

#define FEAT 64
#define SCAN_B 1024
#define STILE 68   // s_tile stride: breaks 4-way LDS bank conflict on k-loop

typedef int      v4i __attribute__((ext_vector_type(4)));
typedef float    v2f __attribute__((ext_vector_type(2)));
typedef float    v4f __attribute__((ext_vector_type(4)));
typedef _Float16 v4h __attribute__((ext_vector_type(4)));
typedef unsigned int u32;

// fp8x4 helpers (OCP e4m3fn on gfx950; encode/decode both on-device)
__device__ __forceinline__ float4 fp8x4_dec(u32 w) {
    v2f lo = __builtin_amdgcn_cvt_pk_f32_fp8((int)w, false);  // bytes 0,1
    v2f hi = __builtin_amdgcn_cvt_pk_f32_fp8((int)w, true);   // bytes 2,3
    return make_float4(lo.x, lo.y, hi.x, hi.y);
}
__device__ __forceinline__ u32 fp8x4_enc(float x, float y, float z, float w) {
    int r = 0;
    r = __builtin_amdgcn_cvt_pk_fp8_f32(x, y, r, false);
    r = __builtin_amdgcn_cvt_pk_fp8_f32(z, w, r, true);
    return (u32)r;
}

// ---------- CSR build ----------
// degree count; atomic return = within-row rank; emit pack=(rank<<16)|src.
__global__ void deg_pack_kernel(const int* __restrict__ dst, const int* __restrict__ src,
                                int* __restrict__ cnt, int* __restrict__ pack, int E4) {
    int i = blockIdx.x * blockDim.x + threadIdx.x;
    if (i < E4) {
        v4i d = __builtin_nontemporal_load(((const v4i*)dst) + i);
        v4i s = __builtin_nontemporal_load(((const v4i*)src) + i);
        v4i r;
        r[0] = (atomicAdd(&cnt[d[0]], 1) << 16) | s[0];
        r[1] = (atomicAdd(&cnt[d[1]], 1) << 16) | s[1];
        r[2] = (atomicAdd(&cnt[d[2]], 1) << 16) | s[2];
        r[3] = (atomicAdd(&cnt[d[3]], 1) << 16) | s[3];
        __builtin_nontemporal_store(r, ((v4i*)pack) + i);
    }
}

// Pass 1: exclusive scan over counts PADDED to multiple of 8 -> rowptr
// (chunk-local), bsum. dinv from RAW count: rsqrt(1+cnt).
__global__ __launch_bounds__(SCAN_B) void scan_partial_kernel(
    const int* __restrict__ cnt, int* __restrict__ rowptr,
    int* __restrict__ bsum, float* __restrict__ dinv, int n) {
    __shared__ int wsum[SCAN_B / 64 + 1];
    const int tid  = threadIdx.x;
    const int lane = tid & 63;
    const int wid  = tid >> 6;
    const int i = blockIdx.x * SCAN_B + tid;

    int vr = (i < n) ? cnt[i] : 0;
    if (i < n) dinv[i] = rsqrtf((float)(1 + vr));
    int v = (vr + 7) & ~7;            // pad each list to multiple of 8
    int incl = v;
#pragma unroll
    for (int off = 1; off < 64; off <<= 1) {
        int t = __shfl_up(incl, off, 64);
        if (lane >= off) incl += t;
    }
    if (lane == 63) wsum[wid] = incl;
    __syncthreads();
    if (tid == 0) {
        int run = 0;
#pragma unroll
        for (int w = 0; w < SCAN_B / 64; ++w) { int t = wsum[w]; wsum[w] = run; run += t; }
        wsum[SCAN_B / 64] = run;
        bsum[blockIdx.x] = run;
    }
    __syncthreads();
    if (i < n) rowptr[i] = incl - v + wsum[wid];
}

// Pass 2 (fused): every block wave-scans bsum (nb<=64) to get its own offset,
// adds it, writes rowptr[n], and fills each list's padding slots with dummy.
__global__ __launch_bounds__(SCAN_B) void scan_finish_kernel(
    const int* __restrict__ cnt, int* __restrict__ rowptr,
    const int* __restrict__ bsum, int* __restrict__ col,
    int n, int nb, int dummy) {
    __shared__ int s_off, s_tot;
    const int tid = threadIdx.x;
    if (tid < 64) {
        int v = (tid < nb) ? bsum[tid] : 0;
        int incl = v;
#pragma unroll
        for (int off = 1; off < 64; off <<= 1) {
            int t = __shfl_up(incl, off, 64);
            if ((tid & 63) >= off) incl += t;
        }
        if (tid == (int)blockIdx.x) s_off = incl - v;  // exclusive offset
        if (tid == 63) s_tot = incl;                   // grand total
    }
    __syncthreads();
    const int i = blockIdx.x * SCAN_B + tid;
    if (i < n) {
        const int rp = rowptr[i] + s_off;
        rowptr[i] = rp;
        const int c = cnt[i];
        const int e = rp + ((c + 7) & ~7);
        for (int p = rp + c; p < e; ++p) col[p] = dummy;
    }
    if (i == 0) rowptr[n] = s_tot;
}

// dst-range-partitioned scatter, 2 passes: q = blockIdx&1 owns dst nodes
// [q*qn, (q+1)*qn) -> contiguous col region. rowptr gather is L2-resident.
// pack = (rank<<16)|src.
__global__ void scatter_kernel(const int* __restrict__ dst, const int* __restrict__ pack,
                               const int* __restrict__ rowptr,
                               int* __restrict__ col, int E4, int qn, int n) {
    const int q = blockIdx.x & 1;
    const int i = (blockIdx.x >> 1) * blockDim.x + threadIdx.x;
    const int nlo = q * qn;
    const int nhi = (nlo + qn < n) ? nlo + qn : n;
    if (i < E4) {
        v4i d = __builtin_nontemporal_load(((const v4i*)dst) + i);
        v4i pk = __builtin_nontemporal_load(((const v4i*)pack) + i);
#pragma unroll
        for (int j = 0; j < 4; ++j) {
            if (d[j] >= nlo && d[j] < nhi) {
                col[rowptr[d[j]] + (pk[j] >> 16)] = pk[j] & 0xFFFF;
            }
        }
    }
}

// P8[i] = fp8x4(x4[i] * dinv[row]); tail block zeroes row N of P8 (u32),
// P2h and P1h (fp16) — all three tables' dummy rows.
__global__ void prescale_kernel(const float* __restrict__ x, const float* __restrict__ dinv,
                                u32* __restrict__ P8, _Float16* __restrict__ P2h,
                                _Float16* __restrict__ P1h, int nq) {
    int i = blockIdx.x * blockDim.x + threadIdx.x;
    if (i < nq) {
        float d = dinv[i >> 4];
        float4 v = ((const float4*)x)[i];
        P8[i] = fp8x4_enc(v.x * d, v.y * d, v.z * d, v.w * d);
    } else if (i < nq + 16) {
        P8[i] = 0u;   // row N of P8 (0x00 = +0.0 in e4m3fn)
        v4h z = {(_Float16)0.f, (_Float16)0.f, (_Float16)0.f, (_Float16)0.f};
        *(v4h*)&P2h[(size_t)i * 4] = z;   // row N of P2h
        *(v4h*)&P1h[(size_t)i * 4] = z;   // row N of P1h
    }
}

// ---------- fused layer: gather-sum (fp32 acc) -> LDS GEMM -> epilogue ----
// 16 nodes/block, 16 lanes/node. IN8=1: table is fp8 u32 (4B/lane, row=64B=
// 1 line, 3.2MB L2-resident); IN8=0: fp16 v4h (8B/lane). Lists padded to x8:
// branch-free 8-wide loop, col read as 2x int4 (cached), 8 gathers in flight,
// 4 independent fp32 accumulators. Dummy entries hit zeroed row N.
// INTER=1: fp16 store (next layer's table); INTER=0: fp32 store.
template<int INTER, int IN8>
__global__ __launch_bounds__(256) void layer_kernel(
    const int* __restrict__ rowptr, const int* __restrict__ col,
    const float* __restrict__ dinv, const void* __restrict__ Xs,
    const float* __restrict__ W, const float* __restrict__ bias,
    void* __restrict__ outv, int n) {
    __shared__ float w_lds[FEAT * FEAT];   // [k][c]
    __shared__ float s_tile[16 * STILE];   // [r][k], padded

    const int t = threadIdx.x;
#pragma unroll
    for (int i = 0; i < 4; ++i) {
        int idx = (i * 256 + t) * 4;
        *(float4*)&w_lds[idx] = *(const float4*)&W[idx];
    }
    __syncthreads();   // W visible; nothing else needs a barrier below

    const int r  = t >> 4;       // local node 0..15
    const int c4 = t & 15;       // feature group
    const int g  = blockIdx.x * 16 + r;
    if (g >= n) return;
    const int f = c4 * 4;

    const u32*      __restrict__ Hu = (const u32*)Xs + c4;        // fp8 path
    const _Float16* __restrict__ Hf = (const _Float16*)Xs + f;    // fp16 path

    auto ld = [&](int c) -> float4 {
        if (IN8) {
            return fp8x4_dec(Hu[(size_t)c * 16]);
        } else {
            const v4h h = *(const v4h*)&Hf[(size_t)c * FEAT];
            return make_float4((float)h[0], (float)h[1], (float)h[2], (float)h[3]);
        }
    };

    // self-loop term (table pre-scaled)
    float4 a0 = ld(g);
    float4 a1 = make_float4(0.f, 0.f, 0.f, 0.f);
    float4 a2 = make_float4(0.f, 0.f, 0.f, 0.f);
    float4 a3 = make_float4(0.f, 0.f, 0.f, 0.f);

    int p = rowptr[g];
    const int end = rowptr[g + 1];   // end - p is a multiple of 8

    for (; p < end; p += 8) {
        const v4i c0 = *(const v4i*)&col[p];
        const v4i c1 = *(const v4i*)&col[p + 4];
        const float4 h0 = ld(c0[0]);
        const float4 h1 = ld(c0[1]);
        const float4 h2 = ld(c0[2]);
        const float4 h3 = ld(c0[3]);
        const float4 h4 = ld(c1[0]);
        const float4 h5 = ld(c1[1]);
        const float4 h6 = ld(c1[2]);
        const float4 h7 = ld(c1[3]);
        a0.x += h0.x; a0.y += h0.y; a0.z += h0.z; a0.w += h0.w;
        a1.x += h1.x; a1.y += h1.y; a1.z += h1.z; a1.w += h1.w;
        a2.x += h2.x; a2.y += h2.y; a2.z += h2.z; a2.w += h2.w;
        a3.x += h3.x; a3.y += h3.y; a3.z += h3.z; a3.w += h3.w;
        a0.x += h4.x; a0.y += h4.y; a0.z += h4.z; a0.w += h4.w;
        a1.x += h5.x; a1.y += h5.y; a1.z += h5.z; a1.w += h5.w;
        a2.x += h6.x; a2.y += h6.y; a2.z += h6.z; a2.w += h6.w;
        a3.x += h7.x; a3.y += h7.y; a3.z += h7.z; a3.w += h7.w;
    }
    float4 S = make_float4((a0.x + a1.x) + (a2.x + a3.x),
                           (a0.y + a1.y) + (a2.y + a3.y),
                           (a0.z + a1.z) + (a2.z + a3.z),
                           (a0.w + a1.w) + (a2.w + a3.w));
    *(float4*)&s_tile[r * STILE + f] = S;
    // no __syncthreads: wave w reads only rows 4w..4w+3, which it wrote

    // in-block GEMM: T[r][f..f+3] = sum_k S[r][k] * W[k][f..f+3]
    float4 acc = make_float4(0.f, 0.f, 0.f, 0.f);
#pragma unroll
    for (int k = 0; k < FEAT; ++k) {
        const float sv = s_tile[r * STILE + k];
        const float4 wv = *(const float4*)&w_lds[k * FEAT + f];
        acc.x += sv * wv.x; acc.y += sv * wv.y;
        acc.z += sv * wv.z; acc.w += sv * wv.w;
    }

    const float dg = dinv[g];
    const float4 bv = *(const float4*)&bias[f];
    float4 o = make_float4(acc.x * dg + bv.x, acc.y * dg + bv.y,
                           acc.z * dg + bv.z, acc.w * dg + bv.w);
    if (INTER) {   // ReLU, then pre-scale for next layer's gather; store fp16
        o.x = fmaxf(o.x, 0.f) * dg; o.y = fmaxf(o.y, 0.f) * dg;
        o.z = fmaxf(o.z, 0.f) * dg; o.w = fmaxf(o.w, 0.f) * dg;
        _Float16* o16 = (_Float16*)outv;
        v4h ov;
        ov[0] = (_Float16)o.x; ov[1] = (_Float16)o.y;
        ov[2] = (_Float16)o.z; ov[3] = (_Float16)o.w;
        *(v4h*)&o16[(size_t)g * FEAT + f] = ov;   // cached: next layer's table
    } else {
        float* o32 = (float*)outv;
        *(float4*)&o32[(size_t)g * FEAT + f] = o;
    }
}

extern "C" void kernel_launch(void* const* d_in, const int* in_sizes, int n_in,
                              void* d_out, int out_size, void* d_ws, size_t ws_size,
                              hipStream_t stream) {
    const float* x  = (const float*)d_in[0];
    const int*   ei = (const int*)d_in[1];
    const float* W0 = (const float*)d_in[2];
    const float* b0 = (const float*)d_in[3];
    const float* W1 = (const float*)d_in[4];
    const float* b1 = (const float*)d_in[5];
    const float* W2 = (const float*)d_in[6];
    const float* b2 = (const float*)d_in[7];
    float* out = (float*)d_out;

    const int N = in_sizes[0] / FEAT;   // 50000
    const int E = in_sizes[1] / 2;      // 800000 (divisible by 4)
    const int* src = ei;
    const int* dst = ei + E;

    const int nbScan = (N + SCAN_B - 1) / SCAN_B;   // 49 (<= 64 for scan_finish)
    const int Ecap = E + 8 * N;                      // padded col capacity

    // workspace layout (64B-aligned regions)
    char* w = (char*)d_ws;
    auto take = [&](size_t bytes) { char* p = w; w += (bytes + 63) & ~(size_t)63; return p; };
    int*      cnt    = (int*)take(sizeof(int) * (size_t)N);
    int*      rowptr = (int*)take(sizeof(int) * (size_t)(N + 1));
    int*      bsum   = (int*)take(sizeof(int) * (size_t)(nbScan + 1));
    int*      col    = (int*)take(sizeof(int) * (size_t)Ecap);
    float*    dinv   = (float*)take(sizeof(float) * (size_t)N);
    u32*      P8     = (u32*)take(sizeof(u32) * ((size_t)(N + 1) * 16));       // fp8 table (L0 in)
    _Float16* P2h    = (_Float16*)take(sizeof(_Float16) * ((size_t)(N + 1) * FEAT));
    _Float16* P1h    = (_Float16*)take(sizeof(_Float16) * ((size_t)(N + 1) * FEAT));
    int*      pack   = (int*)P1h;  // alias: pack (3.2MB) in P1h[0..3.2MB);
                                   // P1h row-N zeroing is at offset 6.4MB (no
                                   // overlap) and L1's P1h writes happen after
                                   // scatter consumed pack (stream-ordered)

    const int tB = 256;
    const int E4  = E / 4;
    const int gE4 = (E4 + tB - 1) / tB;
    const int g16 = (N + 15) / 16;
    const int qn  = (N + 1) / 2;        // nodes per scatter partition (2 passes)
    const int nq  = N * FEAT / 4;       // float4-groups (= u32 count in P8)
    const int gQ  = (nq + 16 + tB - 1) / tB;   // +16 groups for row-N zeroing

    // CSR build (shared by all 3 layers)
    hipMemsetAsync(cnt, 0, sizeof(int) * (size_t)N, stream);
    deg_pack_kernel<<<gE4, tB, 0, stream>>>(dst, src, cnt, pack, E4);
    scan_partial_kernel<<<nbScan, SCAN_B, 0, stream>>>(cnt, rowptr, bsum, dinv, N);
    scan_finish_kernel<<<nbScan, SCAN_B, 0, stream>>>(cnt, rowptr, bsum, col, N, nbScan, N);
    scatter_kernel<<<gE4 * 2, tB, 0, stream>>>(dst, pack, rowptr, col, E4, qn, N);

    // prescale input into fp8 P8; zero row N of P8/P2h/P1h (dummy targets)
    prescale_kernel<<<gQ, tB, 0, stream>>>(x, dinv, P8, P2h, P1h, nq);

    // fused layers: fp8 -> fp16 -> fp16 -> fp32
    layer_kernel<1, 1><<<g16, tB, 0, stream>>>(rowptr, col, dinv, P8,  W0, b0, P2h, N);
    layer_kernel<1, 0><<<g16, tB, 0, stream>>>(rowptr, col, dinv, P2h, W1, b1, P1h, N);
    layer_kernel<0, 0><<<g16, tB, 0, stream>>>(rowptr, col, dinv, P1h, W2, b2, out, N);
}

// Round 19
// 198.624 us; speedup vs baseline: 1.0257x; 1.0144x over previous
//
#include <hip/hip_runtime.h>

// GCN 3-layer forward — FINAL (R25 restore, proven 199.1us): fp16 feature
// table + packed scatter (pack=(rank<<16)|src) + 2-pass dst-partitioned
// scatter + separate prescale.
//   Session ledger (232.8 -> 199.1): fp16 table -25us; pack -2.6; 4-pass
//   scatter -5; 2-pass ~0. Rejected with post-mortems: atomic-slot scatter
//   (+44), col prefetch (0), XCD feature-slice (+82), launch_bounds squeeze
//   (+8), 16B-payload gather (0), nt-col (+5), u16 col (0), x4 padding (0),
//   prescale fusion (+4.6), fp8 tables (accuracy fail all-fp8; perf null
//   single-fp8). Layers pinned ~33us each by random-line service; every
//   first-order lever (bytes/lines/requests/occupancy/residency) nulled.

#define FEAT 64
#define SCAN_B 1024
#define STILE 68   // s_tile stride: breaks 4-way LDS bank conflict on k-loop

typedef int      v4i __attribute__((ext_vector_type(4)));
typedef float    v4f __attribute__((ext_vector_type(4)));
typedef _Float16 v4h __attribute__((ext_vector_type(4)));

// ---------- CSR build ----------
// degree count; atomic return = within-row rank; emit pack=(rank<<16)|src.
__global__ void deg_pack_kernel(const int* __restrict__ dst, const int* __restrict__ src,
                                int* __restrict__ cnt, int* __restrict__ pack, int E4) {
    int i = blockIdx.x * blockDim.x + threadIdx.x;
    if (i < E4) {
        v4i d = __builtin_nontemporal_load(((const v4i*)dst) + i);
        v4i s = __builtin_nontemporal_load(((const v4i*)src) + i);
        v4i r;
        r[0] = (atomicAdd(&cnt[d[0]], 1) << 16) | s[0];
        r[1] = (atomicAdd(&cnt[d[1]], 1) << 16) | s[1];
        r[2] = (atomicAdd(&cnt[d[2]], 1) << 16) | s[2];
        r[3] = (atomicAdd(&cnt[d[3]], 1) << 16) | s[3];
        __builtin_nontemporal_store(r, ((v4i*)pack) + i);
    }
}

// Pass 1: exclusive scan over counts PADDED to multiple of 8 -> rowptr
// (chunk-local), bsum. dinv from RAW count: rsqrt(1+cnt).
__global__ __launch_bounds__(SCAN_B) void scan_partial_kernel(
    const int* __restrict__ cnt, int* __restrict__ rowptr,
    int* __restrict__ bsum, float* __restrict__ dinv, int n) {
    __shared__ int wsum[SCAN_B / 64 + 1];
    const int tid  = threadIdx.x;
    const int lane = tid & 63;
    const int wid  = tid >> 6;
    const int i = blockIdx.x * SCAN_B + tid;

    int vr = (i < n) ? cnt[i] : 0;
    if (i < n) dinv[i] = rsqrtf((float)(1 + vr));
    int v = (vr + 7) & ~7;            // pad each list to multiple of 8
    int incl = v;
#pragma unroll
    for (int off = 1; off < 64; off <<= 1) {
        int t = __shfl_up(incl, off, 64);
        if (lane >= off) incl += t;
    }
    if (lane == 63) wsum[wid] = incl;
    __syncthreads();
    if (tid == 0) {
        int run = 0;
#pragma unroll
        for (int w = 0; w < SCAN_B / 64; ++w) { int t = wsum[w]; wsum[w] = run; run += t; }
        wsum[SCAN_B / 64] = run;
        bsum[blockIdx.x] = run;
    }
    __syncthreads();
    if (i < n) rowptr[i] = incl - v + wsum[wid];
}

// Pass 2 (fused): every block wave-scans bsum (nb<=64) to get its own offset,
// adds it, writes rowptr[n], and fills each list's padding slots with dummy.
__global__ __launch_bounds__(SCAN_B) void scan_finish_kernel(
    const int* __restrict__ cnt, int* __restrict__ rowptr,
    const int* __restrict__ bsum, int* __restrict__ col,
    int n, int nb, int dummy) {
    __shared__ int s_off, s_tot;
    const int tid = threadIdx.x;
    if (tid < 64) {
        int v = (tid < nb) ? bsum[tid] : 0;
        int incl = v;
#pragma unroll
        for (int off = 1; off < 64; off <<= 1) {
            int t = __shfl_up(incl, off, 64);
            if ((tid & 63) >= off) incl += t;
        }
        if (tid == (int)blockIdx.x) s_off = incl - v;  // exclusive offset
        if (tid == 63) s_tot = incl;                   // grand total
    }
    __syncthreads();
    const int i = blockIdx.x * SCAN_B + tid;
    if (i < n) {
        const int rp = rowptr[i] + s_off;
        rowptr[i] = rp;
        const int c = cnt[i];
        const int e = rp + ((c + 7) & ~7);
        for (int p = rp + c; p < e; ++p) col[p] = dummy;
    }
    if (i == 0) rowptr[n] = s_tot;
}

// dst-range-partitioned scatter, 2 passes: q = blockIdx&1 owns dst nodes
// [q*qn, (q+1)*qn) -> contiguous col region. rowptr gather is L2-resident.
// pack = (rank<<16)|src.
__global__ void scatter_kernel(const int* __restrict__ dst, const int* __restrict__ pack,
                               const int* __restrict__ rowptr,
                               int* __restrict__ col, int E4, int qn, int n) {
    const int q = blockIdx.x & 1;
    const int i = (blockIdx.x >> 1) * blockDim.x + threadIdx.x;
    const int nlo = q * qn;
    const int nhi = (nlo + qn < n) ? nlo + qn : n;
    if (i < E4) {
        v4i d = __builtin_nontemporal_load(((const v4i*)dst) + i);
        v4i pk = __builtin_nontemporal_load(((const v4i*)pack) + i);
#pragma unroll
        for (int j = 0; j < 4; ++j) {
            if (d[j] >= nlo && d[j] < nhi) {
                col[rowptr[d[j]] + (pk[j] >> 16)] = pk[j] & 0xFFFF;
            }
        }
    }
}

// P1[i] = fp16(x[i] * dinv[row]); tail block zeroes row N of P1/P2 (dummy).
__global__ void prescale_kernel(const float* __restrict__ x, const float* __restrict__ dinv,
                                _Float16* __restrict__ P1, _Float16* __restrict__ P2, int nq) {
    int i = blockIdx.x * blockDim.x + threadIdx.x;
    if (i < nq) {
        float d = dinv[i >> 4];
        float4 v = ((const float4*)x)[i];
        v4h o;
        o[0] = (_Float16)(v.x * d); o[1] = (_Float16)(v.y * d);
        o[2] = (_Float16)(v.z * d); o[3] = (_Float16)(v.w * d);
        *(v4h*)&P1[(size_t)i * 4] = o;
    } else if (i < nq + 16) {
        v4h z = {(_Float16)0.f, (_Float16)0.f, (_Float16)0.f, (_Float16)0.f};
        *(v4h*)&P1[(size_t)i * 4] = z;   // row N of P1
        *(v4h*)&P2[(size_t)i * 4] = z;   // row N of P2
    }
}

// ---------- fused layer: fp16 gather-sum (fp32 acc) -> LDS GEMM -> epilogue --
// 16 nodes/block, 16 lanes/node (4 halves = 8B/lane). Lists padded to x8:
// branch-free 8-wide loop, col read as 2x int4 (cached: broadcast across the
// node's 16 lanes, reused by all 3 layers), 8 gathers in flight, 4 independent
// fp32 accumulators. Dummy entries hit zeroed row N. Table pre-scaled by dinv.
template<int INTER>
__global__ __launch_bounds__(256) void layer_kernel(
    const int* __restrict__ rowptr, const int* __restrict__ col,
    const float* __restrict__ dinv, const _Float16* __restrict__ Xs,
    const float* __restrict__ W, const float* __restrict__ bias,
    void* __restrict__ outv, int n) {
    __shared__ float w_lds[FEAT * FEAT];   // [k][c]
    __shared__ float s_tile[16 * STILE];   // [r][k], padded

    const int t = threadIdx.x;
#pragma unroll
    for (int i = 0; i < 4; ++i) {
        int idx = (i * 256 + t) * 4;
        *(float4*)&w_lds[idx] = *(const float4*)&W[idx];
    }
    __syncthreads();   // W visible; nothing else needs a barrier below

    const int r  = t >> 4;       // local node 0..15
    const int c4 = t & 15;       // feature group (4 halves)
    const int g  = blockIdx.x * 16 + r;
    if (g >= n) return;
    const int f = c4 * 4;
    const _Float16* __restrict__ Hf = Xs + f;

    // self-loop term (table pre-scaled)
    const v4h sh = *(const v4h*)&Hf[(size_t)g * FEAT];
    float4 a0 = make_float4((float)sh[0], (float)sh[1], (float)sh[2], (float)sh[3]);
    float4 a1 = make_float4(0.f, 0.f, 0.f, 0.f);
    float4 a2 = make_float4(0.f, 0.f, 0.f, 0.f);
    float4 a3 = make_float4(0.f, 0.f, 0.f, 0.f);

    int p = rowptr[g];
    const int end = rowptr[g + 1];   // end - p is a multiple of 8

    for (; p < end; p += 8) {
        const v4i c0 = *(const v4i*)&col[p];
        const v4i c1 = *(const v4i*)&col[p + 4];
        const v4h h0 = *(const v4h*)&Hf[(size_t)c0[0] * FEAT];
        const v4h h1 = *(const v4h*)&Hf[(size_t)c0[1] * FEAT];
        const v4h h2 = *(const v4h*)&Hf[(size_t)c0[2] * FEAT];
        const v4h h3 = *(const v4h*)&Hf[(size_t)c0[3] * FEAT];
        const v4h h4 = *(const v4h*)&Hf[(size_t)c1[0] * FEAT];
        const v4h h5 = *(const v4h*)&Hf[(size_t)c1[1] * FEAT];
        const v4h h6 = *(const v4h*)&Hf[(size_t)c1[2] * FEAT];
        const v4h h7 = *(const v4h*)&Hf[(size_t)c1[3] * FEAT];
        a0.x += (float)h0[0]; a0.y += (float)h0[1]; a0.z += (float)h0[2]; a0.w += (float)h0[3];
        a1.x += (float)h1[0]; a1.y += (float)h1[1]; a1.z += (float)h1[2]; a1.w += (float)h1[3];
        a2.x += (float)h2[0]; a2.y += (float)h2[1]; a2.z += (float)h2[2]; a2.w += (float)h2[3];
        a3.x += (float)h3[0]; a3.y += (float)h3[1]; a3.z += (float)h3[2]; a3.w += (float)h3[3];
        a0.x += (float)h4[0]; a0.y += (float)h4[1]; a0.z += (float)h4[2]; a0.w += (float)h4[3];
        a1.x += (float)h5[0]; a1.y += (float)h5[1]; a1.z += (float)h5[2]; a1.w += (float)h5[3];
        a2.x += (float)h6[0]; a2.y += (float)h6[1]; a2.z += (float)h6[2]; a2.w += (float)h6[3];
        a3.x += (float)h7[0]; a3.y += (float)h7[1]; a3.z += (float)h7[2]; a3.w += (float)h7[3];
    }
    float4 S = make_float4((a0.x + a1.x) + (a2.x + a3.x),
                           (a0.y + a1.y) + (a2.y + a3.y),
                           (a0.z + a1.z) + (a2.z + a3.z),
                           (a0.w + a1.w) + (a2.w + a3.w));
    *(float4*)&s_tile[r * STILE + f] = S;
    // no __syncthreads: wave w reads only rows 4w..4w+3, which it wrote

    // in-block GEMM: T[r][f..f+3] = sum_k S[r][k] * W[k][f..f+3]
    float4 acc = make_float4(0.f, 0.f, 0.f, 0.f);
#pragma unroll
    for (int k = 0; k < FEAT; ++k) {
        const float sv = s_tile[r * STILE + k];
        const float4 wv = *(const float4*)&w_lds[k * FEAT + f];
        acc.x += sv * wv.x; acc.y += sv * wv.y;
        acc.z += sv * wv.z; acc.w += sv * wv.w;
    }

    const float dg = dinv[g];
    const float4 bv = *(const float4*)&bias[f];
    float4 o = make_float4(acc.x * dg + bv.x, acc.y * dg + bv.y,
                           acc.z * dg + bv.z, acc.w * dg + bv.w);
    if (INTER) {   // ReLU, then pre-scale for next layer's gather; store fp16
        o.x = fmaxf(o.x, 0.f) * dg; o.y = fmaxf(o.y, 0.f) * dg;
        o.z = fmaxf(o.z, 0.f) * dg; o.w = fmaxf(o.w, 0.f) * dg;
        _Float16* o16 = (_Float16*)outv;
        v4h ov;
        ov[0] = (_Float16)o.x; ov[1] = (_Float16)o.y;
        ov[2] = (_Float16)o.z; ov[3] = (_Float16)o.w;
        *(v4h*)&o16[(size_t)g * FEAT + f] = ov;   // cached: next layer's table
    } else {
        float* o32 = (float*)outv;
        *(float4*)&o32[(size_t)g * FEAT + f] = o;
    }
}

extern "C" void kernel_launch(void* const* d_in, const int* in_sizes, int n_in,
                              void* d_out, int out_size, void* d_ws, size_t ws_size,
                              hipStream_t stream) {
    const float* x  = (const float*)d_in[0];
    const int*   ei = (const int*)d_in[1];
    const float* W0 = (const float*)d_in[2];
    const float* b0 = (const float*)d_in[3];
    const float* W1 = (const float*)d_in[4];
    const float* b1 = (const float*)d_in[5];
    const float* W2 = (const float*)d_in[6];
    const float* b2 = (const float*)d_in[7];
    float* out = (float*)d_out;

    const int N = in_sizes[0] / FEAT;   // 50000
    const int E = in_sizes[1] / 2;      // 800000 (divisible by 4)
    const int* src = ei;
    const int* dst = ei + E;

    const int nbScan = (N + SCAN_B - 1) / SCAN_B;   // 49 (<= 64 for scan_finish)
    const int Ecap = E + 8 * N;                      // padded col capacity

    // workspace layout (64B-aligned regions)
    char* w = (char*)d_ws;
    auto take = [&](size_t bytes) { char* p = w; w += (bytes + 63) & ~(size_t)63; return p; };
    int*      cnt    = (int*)take(sizeof(int) * (size_t)N);
    int*      rowptr = (int*)take(sizeof(int) * (size_t)(N + 1));
    int*      bsum   = (int*)take(sizeof(int) * (size_t)(nbScan + 1));
    int*      col    = (int*)take(sizeof(int) * (size_t)Ecap);
    float*    dinv   = (float*)take(sizeof(float) * (size_t)N);
    _Float16* P1     = (_Float16*)take(sizeof(_Float16) * ((size_t)(N + 1) * FEAT));
    _Float16* P2     = (_Float16*)take(sizeof(_Float16) * ((size_t)(N + 1) * FEAT));
    int*      pack   = (int*)P2;   // alias: pack (3.2MB <= 6.4MB) dead before
                                   // prescale zeroes row N / layer-0 writes P2

    const int tB = 256;
    const int E4  = E / 4;
    const int gE4 = (E4 + tB - 1) / tB;
    const int g16 = (N + 15) / 16;
    const int qn  = (N + 1) / 2;        // nodes per scatter partition (2 passes)
    const int nq  = N * FEAT / 4;
    const int gQ  = (nq + 16 + tB - 1) / tB;   // +16 groups for row-N zeroing

    // CSR build (shared by all 3 layers)
    hipMemsetAsync(cnt, 0, sizeof(int) * (size_t)N, stream);
    deg_pack_kernel<<<gE4, tB, 0, stream>>>(dst, src, cnt, pack, E4);
    scan_partial_kernel<<<nbScan, SCAN_B, 0, stream>>>(cnt, rowptr, bsum, dinv, N);
    scan_finish_kernel<<<nbScan, SCAN_B, 0, stream>>>(cnt, rowptr, bsum, col, N, nbScan, N);
    scatter_kernel<<<gE4 * 2, tB, 0, stream>>>(dst, pack, rowptr, col, E4, qn, N);

    // prescale input into fp16 P1; zero row N of P1/P2 (dummy gather target)
    prescale_kernel<<<gQ, tB, 0, stream>>>(x, dinv, P1, P2, nq);

    // fused layers
    layer_kernel<1><<<g16, tB, 0, stream>>>(rowptr, col, dinv, P1, W0, b0, P2, N);
    layer_kernel<1><<<g16, tB, 0, stream>>>(rowptr, col, dinv, P2, W1, b1, P1, N);
    layer_kernel<0><<<g16, tB, 0, stream>>>(rowptr, col, dinv, P1, W2, b2, out, N);
}